// Round 2
// baseline (391.119 us; speedup 1.0000x reference)
//
#include <hip/hip_runtime.h>
#include <hip/hip_cooperative_groups.h>

namespace cg = cooperative_groups;

// Problem constants (match reference)
#define BATCH   4096
#define DIM     64
#define NTOT    (BATCH * DIM * DIM)   // 16,777,216 fp32 per tensor
#define NVEC    (NTOT / 4)            // 4,194,304 float4s
#define MRANK   32
#define GAMMA_C   0.1f
#define LAMBDA2_C 0.1f

#define THREADS 256
#define GRID    2048                  // == co-residency capacity at 8 blocks/CU
#define STRIDE  (GRID * THREADS)      // 524,288 float4s
#define ITERS   (NVEC / STRIDE)       // 8 — exact fit, no bounds checks

// ---------------------------------------------------------------------------
// Single cooperative kernel.
//  - All 2048 blocks stream 8 float4-pairs/thread (identical to the 48 µs
//    round-0 kernel) and write one partial each (relaxed AGENT-scope atomic
//    store -> per-store sc flags reach the coherence point; NO threadfence,
//    NO cache-wide invalidate in the hot path — that was round 1's 5x loss).
//  - Block 0 additionally gathers the 32x2 diagonal traces into its own LDS
//    (they never touch global memory).
//  - grid.sync(), then block 0 reduces the 2048 partials, computes the rank
//    loss, writes the 3 outputs. No arrival counter -> no memset dispatch.
// ---------------------------------------------------------------------------
__global__ void __launch_bounds__(THREADS, 8)
fused_loss_kernel(const float* __restrict__ pred, const float* __restrict__ tru,
                  float* __restrict__ ws, float* __restrict__ out)
{
    const int tid = threadIdx.x;
    const int bid = blockIdx.x;
    float* partials = ws;

    __shared__ float smem[THREADS / 64];
    __shared__ float red[2][THREADS];   // block 0 only
    __shared__ float sp[MRANK], st[MRANK];

    // --- block 0: trace gather (32 matrices x 64 diag, 8 per thread) ---
    float tp = 0.0f, tr = 0.0f;
    if (bid == 0) {
        const int mat  = tid >> 3;   // 0..31
        const int part = tid & 7;    // 0..7
        #pragma unroll
        for (int i = 0; i < 8; ++i) {
            const int j = part * 8 + i;
            const size_t off = (size_t)mat * (DIM * DIM) + (size_t)j * (DIM + 1);
            tp += pred[off];
            tr += tru[off];
        }
    }

    // --- streaming sumsq: identical structure to the measured-48µs kernel ---
    const int g = bid * THREADS + tid;
    const float4* __restrict__ p4 = (const float4*)pred;
    const float4* __restrict__ t4 = (const float4*)tru;
    float4 a[ITERS], b[ITERS];
    #pragma unroll
    for (int k = 0; k < ITERS; ++k) a[k] = p4[g + k * STRIDE];
    #pragma unroll
    for (int k = 0; k < ITERS; ++k) b[k] = t4[g + k * STRIDE];

    float acc = 0.0f;
    #pragma unroll
    for (int k = 0; k < ITERS; ++k) {
        const float dx = a[k].x - b[k].x;
        const float dy = a[k].y - b[k].y;
        const float dz = a[k].z - b[k].z;
        const float dw = a[k].w - b[k].w;
        acc += dx * dx + dy * dy + dz * dz + dw * dw;
    }
    #pragma unroll
    for (int off = 32; off > 0; off >>= 1)
        acc += __shfl_down(acc, off, 64);
    if ((tid & 63) == 0) smem[tid >> 6] = acc;
    __syncthreads();
    if (tid == 0)
        __hip_atomic_store(&partials[bid],
                           smem[0] + smem[1] + smem[2] + smem[3],
                           __ATOMIC_RELAXED, __HIP_MEMORY_SCOPE_AGENT);

    if (bid == 0) {
        red[0][tid] = tp;
        red[1][tid] = tr;
        __syncthreads();
        if (tid < MRANK) {
            float s1 = 0.0f, s2 = 0.0f;
            #pragma unroll
            for (int i = 0; i < 8; ++i) {
                s1 += red[0][tid * 8 + i];
                s2 += red[1][tid * 8 + i];
            }
            sp[tid] = s1;
            st[tid] = s2;
        }
    }

    cg::this_grid().sync();   // includes the cross-block visibility protocol

    if (bid != 0) return;

    // --- finish on block 0 ---
    float s = 0.0f;
    #pragma unroll
    for (int k = 0; k < GRID / THREADS; ++k)
        s += __hip_atomic_load(&partials[tid + k * THREADS],
                               __ATOMIC_RELAXED, __HIP_MEMORY_SCOPE_AGENT);
    #pragma unroll
    for (int off = 32; off > 0; off >>= 1)
        s += __shfl_down(s, off, 64);
    if ((tid & 63) == 0) smem[tid >> 6] = s;   // grid.sync separated last use
    __syncthreads();

    float racc = 0.0f;
    if (tid < MRANK) {
        const float pi = sp[tid];
        const float ti = st[tid];
        for (int j = tid + 1; j < MRANK; ++j) {
            const float dt = ti - st[j];
            const float dp = pi - sp[j];
            float c = 0.0f;
            if (dt > 0.0f)      c = fmaxf(-dp + GAMMA_C, 0.0f);
            else if (dt < 0.0f) c = fmaxf( dp + GAMMA_C, 0.0f);
            racc += c;
        }
    }
    if (tid < 64) {
        #pragma unroll
        for (int off = 32; off > 0; off >>= 1)
            racc += __shfl_down(racc, off, 64);
        if (tid == 0) {
            const float total_ss = smem[0] + smem[1] + smem[2] + smem[3];
            const float eff  = total_ss / (float)NTOT;
            const float rank = racc / 496.0f;   // 32*31/2 pairs
            out[0] = eff + LAMBDA2_C * rank;
            out[1] = eff;
            out[2] = rank;
        }
    }
}

// ---------------------------------------------------------------------------
// Fallback pair (round-0 kernels, measured 155 µs end-to-end) — used only if
// the cooperative launch is rejected (e.g. capture incompatibility).
// ---------------------------------------------------------------------------
__global__ void __launch_bounds__(THREADS, 2)
partial_sumsq_kernel(const float4* __restrict__ p, const float4* __restrict__ t,
                     float* __restrict__ partials) {
    const int tid = blockIdx.x * THREADS + threadIdx.x;
    float4 a[ITERS], b[ITERS];
    #pragma unroll
    for (int k = 0; k < ITERS; ++k) a[k] = p[tid + k * STRIDE];
    #pragma unroll
    for (int k = 0; k < ITERS; ++k) b[k] = t[tid + k * STRIDE];
    float acc = 0.0f;
    #pragma unroll
    for (int k = 0; k < ITERS; ++k) {
        const float dx = a[k].x - b[k].x;
        const float dy = a[k].y - b[k].y;
        const float dz = a[k].z - b[k].z;
        const float dw = a[k].w - b[k].w;
        acc += dx * dx + dy * dy + dz * dz + dw * dw;
    }
    #pragma unroll
    for (int off = 32; off > 0; off >>= 1)
        acc += __shfl_down(acc, off, 64);
    __shared__ float smem[THREADS / 64];
    if ((threadIdx.x & 63) == 0) smem[threadIdx.x >> 6] = acc;
    __syncthreads();
    if (threadIdx.x == 0)
        partials[blockIdx.x] = smem[0] + smem[1] + smem[2] + smem[3];
}

__global__ void __launch_bounds__(THREADS)
finish_kernel(const float* __restrict__ p, const float* __restrict__ t,
              const float* __restrict__ partials, float* __restrict__ out) {
    const int tid = threadIdx.x;
    float s = 0.0f;
    #pragma unroll
    for (int k = 0; k < GRID / THREADS; ++k)
        s += partials[tid + k * THREADS];
    const int mat  = tid >> 3;
    const int part = tid & 7;
    float tp = 0.0f, tr = 0.0f;
    #pragma unroll
    for (int i = 0; i < 8; ++i) {
        const int j = part * 8 + i;
        const size_t off = (size_t)mat * (DIM * DIM) + (size_t)j * (DIM + 1);
        tp += p[off];
        tr += t[off];
    }
    #pragma unroll
    for (int off = 32; off > 0; off >>= 1)
        s += __shfl_down(s, off, 64);
    __shared__ float smem[THREADS / 64];
    if ((tid & 63) == 0) smem[tid >> 6] = s;
    __shared__ float redp[THREADS], redt[THREADS];
    redp[tid] = tp;
    redt[tid] = tr;
    __syncthreads();
    __shared__ float sp[MRANK], st[MRANK];
    if (tid < MRANK) {
        float s1 = 0.0f, s2 = 0.0f;
        #pragma unroll
        for (int i = 0; i < 8; ++i) {
            s1 += redp[tid * 8 + i];
            s2 += redt[tid * 8 + i];
        }
        sp[tid] = s1;
        st[tid] = s2;
    }
    __syncthreads();
    float racc = 0.0f;
    if (tid < MRANK) {
        const float pi = sp[tid];
        const float ti = st[tid];
        for (int j = tid + 1; j < MRANK; ++j) {
            const float dt = ti - st[j];
            const float dp = pi - sp[j];
            float c = 0.0f;
            if (dt > 0.0f)      c = fmaxf(-dp + GAMMA_C, 0.0f);
            else if (dt < 0.0f) c = fmaxf( dp + GAMMA_C, 0.0f);
            racc += c;
        }
    }
    if (tid < 64) {
        #pragma unroll
        for (int off = 32; off > 0; off >>= 1)
            racc += __shfl_down(racc, off, 64);
        if (tid == 0) {
            const float total_ss = smem[0] + smem[1] + smem[2] + smem[3];
            const float eff  = total_ss / (float)NTOT;
            const float rank = racc / 496.0f;
            out[0] = eff + LAMBDA2_C * rank;
            out[1] = eff;
            out[2] = rank;
        }
    }
}

extern "C" void kernel_launch(void* const* d_in, const int* in_sizes, int n_in,
                              void* d_out, int out_size, void* d_ws, size_t ws_size,
                              hipStream_t stream) {
    const float* pred = (const float*)d_in[0];
    const float* tru  = (const float*)d_in[1];
    float* out = (float*)d_out;
    float* ws  = (float*)d_ws;   // 2048 partials, fully overwritten each call

    void* args[] = { (void*)&pred, (void*)&tru, (void*)&ws, (void*)&out };
    hipError_t err = hipLaunchCooperativeKernel(
        (const void*)fused_loss_kernel, dim3(GRID), dim3(THREADS),
        args, 0, stream);

    if (err != hipSuccess) {
        // Cooperative path unavailable: proven two-kernel fallback.
        partial_sumsq_kernel<<<GRID, THREADS, 0, stream>>>(
            (const float4*)pred, (const float4*)tru, ws);
        finish_kernel<<<1, THREADS, 0, stream>>>(pred, tru, ws, out);
    }
}

// Round 3
// 150.772 us; speedup vs baseline: 2.5941x; 2.5941x over previous
//
#include <hip/hip_runtime.h>

// Problem constants (match reference)
#define BATCH   4096
#define DIM     64
#define NTOT    (BATCH * DIM * DIM)   // 16,777,216 fp32 per tensor
#define NVEC    (NTOT / 4)            // 4,194,304 float4s
#define MRANK   32
#define GAMMA_C   0.1f
#define LAMBDA2_C 0.1f

#define THREADS 256
#define SBLOCKS 4096
#define ITERS   4                     // NVEC / (SBLOCKS*THREADS) — exact fit
#define CHUNK   (THREADS * ITERS)     // 1024 float4s = 16 KB per tensor per block

// ---------------------------------------------------------------------------
// Kernel 1: per-block partial sum of (pred-true)^2.
// Concurrency-first design (R0 was latency-limited at VGPR=32 / ~3 loads in
// flight; warm==cold timing proved bytes weren't the limit):
//  - contiguous 16 KB chunk per block (DRAM page / L3 sector locality),
//  - all 8 loads (4 pred + 4 true) issued BEFORE any consumption, enforced by
//    sched_barrier(0) so the compiler must keep every result live (~56 VGPR),
//  - ITERS=4 keeps payload under the 64-VGPR line -> full 8 waves/SIMD, so
//    in-flight bytes/CU ≈ 32 waves x 8 KB instead of the previous ~2 KB.
// NO atomics, NO fences: plain store of the partial; kernel-completion flush
// + stream order makes it visible to kernel 2 (R0-proven, absmax=0).
// ---------------------------------------------------------------------------
__global__ void __launch_bounds__(THREADS, 8)
partial_sumsq_kernel(const float4* __restrict__ p, const float4* __restrict__ t,
                     float* __restrict__ partials) {
    const int base = blockIdx.x * CHUNK + threadIdx.x;

    float4 a[ITERS], b[ITERS];
    #pragma unroll
    for (int k = 0; k < ITERS; ++k) {
        a[k] = p[base + k * THREADS];
        b[k] = t[base + k * THREADS];
    }
    // Hard scheduling fence: nothing crosses. All 8 global_load_dwordx4 are
    // in flight before the first subtract executes.
    __builtin_amdgcn_sched_barrier(0);

    float acc = 0.0f;
    #pragma unroll
    for (int k = 0; k < ITERS; ++k) {
        const float dx = a[k].x - b[k].x;
        const float dy = a[k].y - b[k].y;
        const float dz = a[k].z - b[k].z;
        const float dw = a[k].w - b[k].w;
        acc += dx * dx + dy * dy + dz * dz + dw * dw;
    }

    #pragma unroll
    for (int off = 32; off > 0; off >>= 1)
        acc += __shfl_down(acc, off, 64);

    __shared__ float smem[THREADS / 64];
    if ((threadIdx.x & 63) == 0) smem[threadIdx.x >> 6] = acc;
    __syncthreads();
    if (threadIdx.x == 0)
        partials[blockIdx.x] = smem[0] + smem[1] + smem[2] + smem[3];
}

// ---------------------------------------------------------------------------
// Kernel 2: one block. Reduce 4096 partials; gather 32x2 traces; rank loss;
// write the 3 outputs. (~5 µs, latency-bound, not worth further work.)
// ---------------------------------------------------------------------------
__global__ void __launch_bounds__(THREADS)
finish_kernel(const float* __restrict__ p, const float* __restrict__ t,
              const float* __restrict__ partials, float* __restrict__ out) {
    const int tid = threadIdx.x;

    // --- reduce 4096 partials: 16 per thread ---
    float s = 0.0f;
    #pragma unroll
    for (int k = 0; k < SBLOCKS / THREADS; ++k)
        s += partials[tid + k * THREADS];

    // --- trace gather (independent loads, overlap with the above) ---
    const int mat  = tid >> 3;   // 0..31
    const int part = tid & 7;    // 0..7
    float tp = 0.0f, tr = 0.0f;
    #pragma unroll
    for (int i = 0; i < 8; ++i) {
        const int j = part * 8 + i;
        const size_t off = (size_t)mat * (DIM * DIM) + (size_t)j * (DIM + 1);
        tp += p[off];
        tr += t[off];
    }

    // block-reduce sumsq
    #pragma unroll
    for (int off = 32; off > 0; off >>= 1)
        s += __shfl_down(s, off, 64);
    __shared__ float smem[THREADS / 64];
    if ((tid & 63) == 0) smem[tid >> 6] = s;

    // per-matrix traces via LDS
    __shared__ float redp[THREADS], redt[THREADS];
    redp[tid] = tp;
    redt[tid] = tr;
    __syncthreads();

    __shared__ float sp[MRANK], st[MRANK];
    if (tid < MRANK) {
        float s1 = 0.0f, s2 = 0.0f;
        #pragma unroll
        for (int i = 0; i < 8; ++i) {
            s1 += redp[tid * 8 + i];
            s2 += redt[tid * 8 + i];
        }
        sp[tid] = s1;
        st[tid] = s2;
    }
    __syncthreads();

    float racc = 0.0f;
    if (tid < MRANK) {
        const float pi = sp[tid];
        const float ti = st[tid];
        for (int j = tid + 1; j < MRANK; ++j) {
            const float dt = ti - st[j];
            const float dp = pi - sp[j];
            float c = 0.0f;
            if (dt > 0.0f)      c = fmaxf(-dp + GAMMA_C, 0.0f);
            else if (dt < 0.0f) c = fmaxf( dp + GAMMA_C, 0.0f);
            racc += c;
        }
    }
    if (tid < 64) {
        #pragma unroll
        for (int off = 32; off > 0; off >>= 1)
            racc += __shfl_down(racc, off, 64);
        if (tid == 0) {
            const float total_ss = smem[0] + smem[1] + smem[2] + smem[3];
            const float eff  = total_ss / (float)NTOT;
            const float rank = racc / 496.0f;   // 32*31/2 pairs
            out[0] = eff + LAMBDA2_C * rank;
            out[1] = eff;
            out[2] = rank;
        }
    }
}

extern "C" void kernel_launch(void* const* d_in, const int* in_sizes, int n_in,
                              void* d_out, int out_size, void* d_ws, size_t ws_size,
                              hipStream_t stream) {
    const float* pred = (const float*)d_in[0];
    const float* tru  = (const float*)d_in[1];
    float* out = (float*)d_out;
    float* ws  = (float*)d_ws;   // 4096 floats of partials — fully overwritten
                                 // by kernel 1 every call, no init needed.

    partial_sumsq_kernel<<<SBLOCKS, THREADS, 0, stream>>>(
        (const float4*)pred, (const float4*)tru, ws);

    finish_kernel<<<1, THREADS, 0, stream>>>(pred, tru, ws, out);
}